// Round 1
// baseline (14.649 us; speedup 1.0000x reference)
//
#include <hip/hip_runtime.h>
#include <hip/hip_bf16.h>
#include <math.h>

// Problem constants (from reference setup_inputs): B=256, H=32, S=16, D=128
#define NB 256
#define NH 32
#define NS 16
#define ND 128
#define MIN_BLOCK_KV 32

// One wave (64 lanes) per (b,h) row. Each lane handles 2 consecutive floats
// of the D=128 output (float2, 8 B/lane). 4 rows per 256-thread block.
__global__ __launch_bounds__(256) void merge_splits_kernel(
    const float* __restrict__ att_out,    // [B,H,S,D]
    const float* __restrict__ att_lse,    // [B,H,S]
    const int*   __restrict__ kv_indptr,  // [B+1]
    const int*   __restrict__ num_splits, // [B]
    float*       __restrict__ out)        // [B,H,D]
{
    const int row  = blockIdx.x * 4 + (threadIdx.x >> 6);   // b*NH + h
    const int lane = threadIdx.x & 63;
    if (row >= NB * NH) return;
    const int b = row >> 5;   // NH == 32

    // Wave-uniform split geometry
    const int seq_len = kv_indptr[b + 1] - kv_indptr[b];
    const int splits  = num_splits[b];
    int ps = (seq_len + splits - 1) / splits;               // cdiv(seq_len, splits)
    ps = ((ps + MIN_BLOCK_KV - 1) / MIN_BLOCK_KV) * MIN_BLOCK_KV;  // round up to 32

    // LSE row (16 floats, wave-uniform broadcast loads) -> masked max
    const float* lse_ptr = att_lse + (size_t)row * NS;
    float w[NS];
    float m = -INFINITY;
#pragma unroll
    for (int s = 0; s < NS; ++s) {
        const bool valid = (ps * s) < seq_len;   // ps*15 <= 122880, no overflow
        const float l = valid ? lse_ptr[s] : -INFINITY;
        w[s] = l;
        m = fmaxf(m, l);
    }

    float esum = 0.f;
#pragma unroll
    for (int s = 0; s < NS; ++s) {
        const float e = (w[s] == -INFINITY) ? 0.f : __expf(w[s] - m);
        w[s] = e;
        esum += e;
    }

    // Weighted sum over valid splits; skip loads where w==0 (wave-uniform branch)
    const float2* __restrict__ src =
        (const float2*)(att_out + (size_t)row * NS * ND);
    float accx = 0.f, accy = 0.f;
#pragma unroll
    for (int s = 0; s < NS; ++s) {
        if (w[s] != 0.f) {
            const float2 v = src[s * (ND / 2) + lane];
            accx = fmaf(w[s], v.x, accx);
            accy = fmaf(w[s], v.y, accy);
        }
    }

    const float inv = 1.f / esum;
    float2* dst = (float2*)(out + (size_t)row * ND);
    dst[lane] = make_float2(accx * inv, accy * inv);
}

extern "C" void kernel_launch(void* const* d_in, const int* in_sizes, int n_in,
                              void* d_out, int out_size, void* d_ws, size_t ws_size,
                              hipStream_t stream) {
    const float* att_out    = (const float*)d_in[0];
    const float* att_lse    = (const float*)d_in[1];
    // d_in[2] = q (unused), d_in[3] = v_buffer (unused)
    const int*   kv_indptr  = (const int*)d_in[4];
    const int*   num_splits = (const int*)d_in[5];
    float* out = (float*)d_out;

    const int rows = NB * NH;              // 8192
    const int blocks = rows / 4;           // 2048 blocks of 256 threads
    merge_splits_kernel<<<blocks, 256, 0, stream>>>(
        att_out, att_lse, kv_indptr, num_splits, out);
}

// Round 2
// 11.511 us; speedup vs baseline: 1.2726x; 1.2726x over previous
//
#include <hip/hip_runtime.h>
#include <hip/hip_bf16.h>
#include <math.h>

// Problem constants: B=256, H=32, S=16, D=128
#define NB 256
#define NH 32
#define NS 16
#define ND 128

// One 64-lane wave handles TWO consecutive rows (b*32+h pairs share b, so
// split geometry is wave-uniform). Each half-wave (32 lanes) owns one row;
// lane handles one float4 (16B) of the D=128 row. Loads for all valid splits
// are issued before any FMA (load-all-then-fma) for max MLP; valid splits are
// a prefix s < nvalid, so guards are wave-uniform scalar branches.
__global__ __launch_bounds__(256) void merge_splits_kernel(
    const float* __restrict__ att_out,    // [B,H,S,D]
    const float* __restrict__ att_lse,    // [B,H,S]
    const int*   __restrict__ kv_indptr,  // [B+1]
    const int*   __restrict__ num_splits, // [B]
    float*       __restrict__ out)        // [B,H,D]
{
    const int wid  = threadIdx.x >> 6;        // wave in block: 0..3
    const int lane = threadIdx.x & 63;
    const int half = lane >> 5;               // which of the 2 rows
    const int l    = lane & 31;               // float4 index within row
    const int row  = blockIdx.x * 8 + wid * 2 + half;   // b*NH + h
    const int b    = row >> 5;                // NH == 32

    // Wave-uniform split geometry (both rows share b)
    const int seq_len = kv_indptr[b + 1] - kv_indptr[b];
    const int splits  = num_splits[b];
    int ps = (seq_len + splits - 1) / splits;         // cdiv
    ps = ((ps + 31) >> 5) << 5;                       // round up to 32
    const int nvalid = (seq_len + ps - 1) / ps;       // 1..16, prefix of valid splits

    // LSE row: 16 floats as 4x float4 (per-half-wave broadcast)
    const float4* lse4 = (const float4*)(att_lse + (size_t)row * NS);
    const float4 L0 = lse4[0], L1 = lse4[1], L2 = lse4[2], L3 = lse4[3];
    float w[NS] = {L0.x, L0.y, L0.z, L0.w, L1.x, L1.y, L1.z, L1.w,
                   L2.x, L2.y, L2.z, L2.w, L3.x, L3.y, L3.z, L3.w};

    float m = -INFINITY;
#pragma unroll
    for (int s = 0; s < NS; ++s) {
        const float li = (s < nvalid) ? w[s] : -INFINITY;
        w[s] = li;
        m = fmaxf(m, li);
    }
    float esum = 0.f;
#pragma unroll
    for (int s = 0; s < NS; ++s) {
        w[s] = __expf(w[s] - m);     // exp(-inf) == 0 for invalid splits
        esum += w[s];
    }

    // Issue ALL valid-split loads before any FMA (max outstanding loads).
    const float4* __restrict__ src =
        (const float4*)(att_out + (size_t)row * NS * ND);
    float4 v[NS];
#pragma unroll
    for (int s = 0; s < NS; ++s) v[s] = make_float4(0.f, 0.f, 0.f, 0.f);
#pragma unroll
    for (int s = 0; s < NS; ++s) {
        if (s < nvalid) v[s] = src[s * (ND / 4) + l];   // uniform scalar branch
    }

    float4 acc = make_float4(0.f, 0.f, 0.f, 0.f);
#pragma unroll
    for (int s = 0; s < NS; ++s) {
        acc.x = fmaf(w[s], v[s].x, acc.x);
        acc.y = fmaf(w[s], v[s].y, acc.y);
        acc.z = fmaf(w[s], v[s].z, acc.z);
        acc.w = fmaf(w[s], v[s].w, acc.w);
    }

    const float inv = 1.f / esum;
    float4* dst = (float4*)(out + (size_t)row * ND);
    dst[l] = make_float4(acc.x * inv, acc.y * inv, acc.z * inv, acc.w * inv);
}

extern "C" void kernel_launch(void* const* d_in, const int* in_sizes, int n_in,
                              void* d_out, int out_size, void* d_ws, size_t ws_size,
                              hipStream_t stream) {
    const float* att_out    = (const float*)d_in[0];
    const float* att_lse    = (const float*)d_in[1];
    // d_in[2] = q (unused), d_in[3] = v_buffer (unused)
    const int*   kv_indptr  = (const int*)d_in[4];
    const int*   num_splits = (const int*)d_in[5];
    float* out = (float*)d_out;

    const int rows = NB * NH;                 // 8192
    const int blocks = rows / 8;              // 1024 blocks x 256 threads (2 rows/wave)
    merge_splits_kernel<<<blocks, 256, 0, stream>>>(
        att_out, att_lse, kv_indptr, num_splits, out);
}

// Round 3
// 10.810 us; speedup vs baseline: 1.3552x; 1.0649x over previous
//
#include <hip/hip_runtime.h>
#include <hip/hip_bf16.h>
#include <math.h>

// Problem constants: B=256, H=32, S=16, D=128
#define NB 256
#define NH 32
#define NS 16
#define ND 128

// One 64-lane wave per block handles TWO consecutive rows (rows 2p,2p+1 always
// share batch b, so split geometry is wave-uniform). Each half-wave (32 lanes)
// owns one row; each lane one float4 (16B). All 16 att loads are issued
// BRANCHLESSLY with a clamped split index (valid splits are a prefix; the
// duplicated tail loads hit L1 and their weights are exactly 0), so the load
// stream is 16 back-to-back global_load_dwordx4 overlapping the exp math.
__global__ __launch_bounds__(64) void merge_splits_kernel(
    const float* __restrict__ att_out,    // [B,H,S,D]
    const float* __restrict__ att_lse,    // [B,H,S]
    const int*   __restrict__ kv_indptr,  // [B+1]
    const int*   __restrict__ num_splits, // [B]
    float*       __restrict__ out)        // [B,H,D]
{
    const int lane = threadIdx.x;             // 0..63
    const int half = lane >> 5;               // which of the 2 rows
    const int l    = lane & 31;               // float4 index within row
    const int row  = blockIdx.x * 2 + half;   // b*NH + h
    const int b    = row >> 5;                // NH == 32 (uniform: rows differ in bit0 only)

    // Wave-uniform split geometry
    const int seq_len = kv_indptr[b + 1] - kv_indptr[b];
    const int splits  = num_splits[b];
    int ps = (seq_len + splits - 1) / splits;         // cdiv
    ps = ((ps + 31) >> 5) << 5;                       // round up to 32
    const int nvalid = (seq_len + ps - 1) / ps;       // 1..16 (prefix of valid splits)

    // LSE row: 16 floats as 4x float4 (issued first, in flight with att loads)
    const float4* lse4 = (const float4*)(att_lse + (size_t)row * NS);
    const float4 L0 = lse4[0], L1 = lse4[1], L2 = lse4[2], L3 = lse4[3];

    // Branchless att loads: clamp split index to the valid prefix.
    const float4* __restrict__ src =
        (const float4*)(att_out + (size_t)row * NS * ND);
    const int nvm1 = nvalid - 1;
    float4 v[NS];
#pragma unroll
    for (int s = 0; s < NS; ++s) {
        const int sc = (s < nvalid) ? s : nvm1;       // uniform s_cselect
        v[s] = src[sc * (ND / 4) + l];
    }

    // Softmax weights over the valid prefix (overlaps load latency).
    float w[NS] = {L0.x, L0.y, L0.z, L0.w, L1.x, L1.y, L1.z, L1.w,
                   L2.x, L2.y, L2.z, L2.w, L3.x, L3.y, L3.z, L3.w};
    float m = -INFINITY;
#pragma unroll
    for (int s = 0; s < NS; ++s) {
        const float li = (s < nvalid) ? w[s] : -INFINITY;
        w[s] = li;
        m = fmaxf(m, li);
    }
    float esum = 0.f;
#pragma unroll
    for (int s = 0; s < NS; ++s) {
        w[s] = __expf(w[s] - m);     // exp(-inf) == 0 for invalid splits
        esum += w[s];
    }

    float4 acc = make_float4(0.f, 0.f, 0.f, 0.f);
#pragma unroll
    for (int s = 0; s < NS; ++s) {
        acc.x = fmaf(w[s], v[s].x, acc.x);
        acc.y = fmaf(w[s], v[s].y, acc.y);
        acc.z = fmaf(w[s], v[s].z, acc.z);
        acc.w = fmaf(w[s], v[s].w, acc.w);
    }

    const float inv = 1.f / esum;
    float4* dst = (float4*)(out + (size_t)row * ND);
    dst[l] = make_float4(acc.x * inv, acc.y * inv, acc.z * inv, acc.w * inv);
}

extern "C" void kernel_launch(void* const* d_in, const int* in_sizes, int n_in,
                              void* d_out, int out_size, void* d_ws, size_t ws_size,
                              hipStream_t stream) {
    const float* att_out    = (const float*)d_in[0];
    const float* att_lse    = (const float*)d_in[1];
    // d_in[2] = q (unused), d_in[3] = v_buffer (unused)
    const int*   kv_indptr  = (const int*)d_in[4];
    const int*   num_splits = (const int*)d_in[5];
    float* out = (float*)d_out;

    const int pairs = NB * NH / 2;            // 4096 row-pairs
    merge_splits_kernel<<<pairs, 64, 0, stream>>>(
        att_out, att_lse, kv_indptr, num_splits, out);
}